// Round 16
// baseline (351.346 us; speedup 1.0000x reference)
//
#include <hip/hip_runtime.h>

#define BATCH 8192
#define DIM   2048   // IN_DIM == OUT_DIM
#define DEPTH 5

// ============================================================================
// r13: r10's verified 256x256 quarter-pipeline GEMM + prep-fold.
//
// r10 measured: GEMM 156us, MfmaUtil 60.9% (= plain-HIP template level,
// m201's 62.1%). Non-GEMM residue ~170us, of which prep's x-split branch
// (64MB read + 64MB write streaming) ~20-25us is removable: fold the
// f32->bf16 hi/lo split into the GEMM's A staging (T14 reg-staging).
//
// A-staging (replaces GLDS for A): per thread, row_local = wave*32+(lane>>1),
// khalf = lane&1 covers x[bm*256+row_local][kt*32+khalf*16 .. +16) via 4x
// float4 (issued at iter top; L2-resident by q1). After q1: split to bf16
// hi/lo (identical RNE formulas -> bit-identical operands to r10) and
// 4x ds_write_b128 into the SAME physical swizzled layout GLDS produced:
// phys granule = logical ^ s, s = (row>>1)&3 = (lane>>2)&3. Bank check:
// each 8-lane group hits all 32 banks exactly once -> conflict-free.
//
// Hazards (same sync skeleton as r10, HW-verified):
//  - A ds_writes (into so, after q1 of t) vs so's prior readers: so(t)'s
//    last readers are iter-(t-1) q0-q2 reads, lgkm-drained before
//    mid-barrier(t-1); post-barrier(t-1) LDS reads touch only bo(t)-parity
//    buffers. Any wave at q1(t) implies all waves passed mid-barrier(t-1).
//  - A ds_writes vs seam A(t+1) read (end of t, reads so(t)): drained by
//    mid-iter lgkmcnt(0) + barrier (collective) before the seam. RAW safe.
//  - B GLDS: unchanged (vmcnt(0) at mid-iter, loads aged ~2900 cyc).
// ============================================================================

#define BUFSZ  65536
#define ABYTES 32768

typedef short bf16x8_t __attribute__((ext_vector_type(8)));
typedef float f32x4_t  __attribute__((ext_vector_type(4)));

// ---- bf16 split helpers (RNE, bit-manip) ----
__device__ __forceinline__ unsigned short f2bf(float f) {
  unsigned u = __float_as_uint(f);
  u += 0x7fffu + ((u >> 16) & 1u);
  return (unsigned short)(u >> 16);
}
__device__ __forceinline__ float bf2f(unsigned short h) {
  return __uint_as_float(((unsigned)h) << 16);
}

// ============================================================================
// Prep (one dispatch, 4104 blocks) -- x-split branch REMOVED (folded into
// GEMM). W-transpose+split and bias2 branches unchanged (verified r4-r10).
//  blocks [0, 4096)    : W (KxN) -> transpose+split -> whi/wlo [N][K] bf16
//  blocks [4096, 4104) : bias2[j] = b[j] + (1/2048)*prod_d cos(hdw[d,j,0])^2
// ============================================================================
__global__ void prep_fused_kernel(const float* __restrict__ hdw,
                                  const float* __restrict__ W,
                                  const float* __restrict__ bias,
                                  float* __restrict__ bias2,
                                  unsigned short* __restrict__ whi,
                                  unsigned short* __restrict__ wlo) {
  __shared__ float tile[32][33];
  const int b = blockIdx.x;
  const int tid = threadIdx.x;

  if (b < 4096) {  // ---- transpose + split W -> [N][K] ----
    const int t = b;                 // 4096 tiles of 32x32
    const int k0 = (t >> 6) * 32;
    const int n0 = (t & 63) * 32;
    const int tx = tid & 31;   // n within tile
    const int ty = tid >> 5;   // k within tile (8 rows/iter)
#pragma unroll
    for (int r = 0; r < 32; r += 8)
      tile[ty + r][tx] = W[(size_t)(k0 + ty + r) * DIM + n0 + tx];
    __syncthreads();
    const int n = tid >> 3;          // 0..31
    const int kq = (tid & 7) * 4;    // 0..28
    ushort4 hv, lv;
    float vv0 = tile[kq + 0][n], vv1 = tile[kq + 1][n];
    float vv2 = tile[kq + 2][n], vv3 = tile[kq + 3][n];
    hv.x = f2bf(vv0); lv.x = f2bf(vv0 - bf2f(hv.x));
    hv.y = f2bf(vv1); lv.y = f2bf(vv1 - bf2f(hv.y));
    hv.z = f2bf(vv2); lv.z = f2bf(vv2 - bf2f(hv.z));
    hv.w = f2bf(vv3); lv.w = f2bf(vv3 - bf2f(hv.w));
    const size_t o = (size_t)(n0 + n) * DIM + k0 + kq;
    *(ushort4*)(whi + o) = hv;
    *(ushort4*)(wlo + o) = lv;
  } else {  // ---- bias2 (scan preserves axis-1 uniformity -> rolls cancel) ----
    int j = (b - 4096) * 256 + tid;
    float p = 1.0f;
#pragma unroll
    for (int d = 0; d < DEPTH; ++d)
      p *= cosf(hdw[(size_t)d * DIM * DIM + (size_t)j * DIM]);
    bias2[j] = bias[j] + p * p * (1.0f / 2048.0f);
  }
}

// ---- async global->LDS, 16B per lane, LDS dest = wave-uniform base + lane*16
#define GLDS(SRC, OFF)                                                         \
  __builtin_amdgcn_global_load_lds(                                            \
      (const __attribute__((address_space(1))) unsigned int*)(SRC),            \
      (__attribute__((address_space(3))) unsigned int*)(smem + (OFF)), 16, 0, 0)

#define MFMA16(A, B, C) __builtin_amdgcn_mfma_f32_16x16x32_bf16((A), (B), (C), 0, 0, 0)

// stage B half of one tile (k-element offset KO) into buffer at byte SO
#define STAGE_B(KO, SO)                                                        \
  do {                                                                         \
    GLDS(sBh + (KO),             (SO) + ABYTES + 0     + wdst);                \
    GLDS(sBh + 128 * DIM + (KO), (SO) + ABYTES + 8192  + wdst);                \
    GLDS(sBl + (KO),             (SO) + ABYTES + 16384 + wdst);                \
    GLDS(sBl + 128 * DIM + (KO), (SO) + ABYTES + 24576 + wdst);                \
  } while (0)

// issue the 4 float4 loads of this thread's 16 x-floats for k-tile offset KO
#define ALOAD(KO)                                                              \
  do {                                                                         \
    xf0 = *(const float4*)(xsrc + (KO));                                       \
    xf1 = *(const float4*)(xsrc + (KO) + 4);                                   \
    xf2 = *(const float4*)(xsrc + (KO) + 8);                                   \
    xf3 = *(const float4*)(xsrc + (KO) + 12);                                  \
  } while (0)

// split xf0..xf3 -> bf16 hi/lo and ds_write into A region of buffer SO
#define ASPLIT_WRITE(SO)                                                       \
  do {                                                                         \
    float f[16] = {xf0.x, xf0.y, xf0.z, xf0.w, xf1.x, xf1.y, xf1.z, xf1.w,     \
                   xf2.x, xf2.y, xf2.z, xf2.w, xf3.x, xf3.y, xf3.z, xf3.w};    \
    bf16x8_t h0, l0, h1, l1;                                                   \
    _Pragma("unroll")                                                          \
    for (int j = 0; j < 8; ++j) {                                              \
      unsigned short hj = f2bf(f[j]);                                          \
      h0[j] = (short)hj;                                                       \
      l0[j] = (short)f2bf(f[j] - bf2f(hj));                                    \
    }                                                                          \
    _Pragma("unroll")                                                          \
    for (int j = 0; j < 8; ++j) {                                              \
      unsigned short hj = f2bf(f[8 + j]);                                      \
      h1[j] = (short)hj;                                                       \
      l1[j] = (short)f2bf(f[8 + j] - bf2f(hj));                                \
    }                                                                          \
    *(bf16x8_t*)(smem + (SO) + ad0)         = h0;                              \
    *(bf16x8_t*)(smem + (SO) + ad0 + 16384) = l0;                              \
    *(bf16x8_t*)(smem + (SO) + ad1)         = h1;                              \
    *(bf16x8_t*)(smem + (SO) + ad1 + 16384) = l1;                              \
  } while (0)

// read one B quarter (nt = NT, NT+1) from buffer base PB into 4 named regs
#define READ_BQ(PB, NT, H0, L0, H1, L1)                                        \
  do {                                                                         \
    H0 = *(const bf16x8_t*)((PB) + (NT) * 1024);                               \
    L0 = *(const bf16x8_t*)((PB) + 16384 + (NT) * 1024);                       \
    H1 = *(const bf16x8_t*)((PB) + ((NT) + 1) * 1024);                         \
    L1 = *(const bf16x8_t*)((PB) + 16384 + ((NT) + 1) * 1024);                 \
  } while (0)

// 24 MFMA: quarter with B regs (H0,L0,H1,L1) into acc columns C0, C0+1
#define QMFMA(H0, L0, H1, L1, C0)                                              \
  do {                                                                         \
    __builtin_amdgcn_s_setprio(1);                                             \
    _Pragma("unroll")                                                          \
    for (int mt = 0; mt < 4; ++mt) {                                           \
      acc[mt][C0]     = MFMA16(A_h[mt], H0, acc[mt][C0]);                      \
      acc[mt][C0]     = MFMA16(A_h[mt], L0, acc[mt][C0]);                      \
      acc[mt][C0]     = MFMA16(A_l[mt], H0, acc[mt][C0]);                      \
      acc[mt][C0 + 1] = MFMA16(A_h[mt], H1, acc[mt][C0 + 1]);                  \
      acc[mt][C0 + 1] = MFMA16(A_h[mt], L1, acc[mt][C0 + 1]);                  \
      acc[mt][C0 + 1] = MFMA16(A_l[mt], H1, acc[mt][C0 + 1]);                  \
    }                                                                          \
    __builtin_amdgcn_s_setprio(0);                                             \
  } while (0)

__global__ __launch_bounds__(512, 2) void gemm_pipe_kernel(
    const float* __restrict__ X,
    const unsigned short* __restrict__ Bh, const unsigned short* __restrict__ Bl,
    const float* __restrict__ bias2, float* __restrict__ out) {
  __shared__ float4 smem4[2 * BUFSZ / 16];
  char* smem = (char*)smem4;

  const int tid  = threadIdx.x;
  const int lane = tid & 63;
  const int wave = tid >> 6;
  const int wm   = wave >> 1;      // 0..3 : 64-row strip within 256
  const int wn   = wave & 1;       // 0..1 : 128-col strip within 256
  const int l15  = lane & 15;
  const int kl   = lane >> 4;
  const int bm = blockIdx.x;       // 32 strips of 256 rows
  const int bn = blockIdx.y;       // 8 strips of 256 cols

  // ---- B staging sources (inverse-swizzled global granule; r8-verified) ----
  const int rsub = wave * 16 + (lane >> 2);                 // 0..127
  const int kg   = ((lane & 3) ^ ((lane >> 3) & 3)) * 8;    // element offset
  const unsigned short* sBh = Bh + ((size_t)(bn * 256 + rsub)) * DIM + kg;
  const unsigned short* sBl = Bl + ((size_t)(bn * 256 + rsub)) * DIM + kg;
  const unsigned wdst = wave * 1024;   // wave-uniform byte base per instr

  // ---- A reg-staging source + swizzled ds_write dests ----
  // row_local = wave*32 + (lane>>1), khalf = lane&1; 16 floats per thread.
  // phys granule = logical ^ s, s = (row_local>>1)&3 = (lane>>2)&3.
  const int row_local = wave * 32 + (lane >> 1);
  const int khalf     = lane & 1;
  const int sA        = (lane >> 2) & 3;
  const float* xsrc = X + (size_t)(bm * 256 + row_local) * DIM + khalf * 16;
  const int ad0 = row_local * 64 + (((khalf * 2 + 0) ^ sA) * 16);
  const int ad1 = row_local * 64 + (((khalf * 2 + 1) ^ sA) * 16);
  float4 xf0, xf1, xf2, xf3;

  // ---- fragment read offset (matching swizzle; unchanged) ----
  const int foff = l15 * 64 + ((kl * 16) ^ (((l15 >> 1) & 3) << 4));

  const f32x4_t vzero = {0.f, 0.f, 0.f, 0.f};
  f32x4_t acc[4][8];
#pragma unroll
  for (int i = 0; i < 4; ++i)
#pragma unroll
    for (int j = 0; j < 8; ++j) acc[i][j] = vzero;

  bf16x8_t A_h[4], A_l[4];
  bf16x8_t Bc_h0, Bc_l0, Bc_h1, Bc_l1;   // "current" B set
  bf16x8_t Bn_h0, Bn_l0, Bn_h1, Bn_l1;   // "next" B set

  // ---- prologue: stage tile 0 -> buf0 (A via reg-split, B via GLDS) ----
  ALOAD(0);
  STAGE_B(0, 0);
  ASPLIT_WRITE(0);
  asm volatile("s_waitcnt vmcnt(0) lgkmcnt(0)" ::: "memory");
  asm volatile("s_barrier" ::: "memory");
  {
    const char* pA0 = smem + wm * 4096 + foff;
#pragma unroll
    for (int mt = 0; mt < 4; ++mt) {
      A_h[mt] = *(const bf16x8_t*)(pA0 + mt * 1024);
      A_l[mt] = *(const bf16x8_t*)(pA0 + 16384 + mt * 1024);
    }
    const char* pB0 = smem + ABYTES + wn * 8192 + foff;
    READ_BQ(pB0, 0, Bc_h0, Bc_l0, Bc_h1, Bc_l1);
  }

#pragma unroll 1
  for (int t = 0; t < 64; ++t) {
    const unsigned bo = (unsigned)(t & 1) * BUFSZ;   // compute buffer
    const unsigned so = bo ^ BUFSZ;                  // stage buffer
    const char* pB = smem + bo + ABYTES + wn * 8192 + foff;

    // ---- stage tile t+1: issue x loads + B GLDS at iter top ----
    if (t < 63) {
      const int ko = (t + 1) * 32;
      ALOAD(ko);
      STAGE_B(ko, so);
    }

    // q0: read quarter1 -> Bn ; MFMA quarter0 (Bc) -> cols 0,1
    READ_BQ(pB, 2, Bn_h0, Bn_l0, Bn_h1, Bn_l1);
    QMFMA(Bc_h0, Bc_l0, Bc_h1, Bc_l1, 0);

    // q1: read quarter2 -> Bc ; MFMA quarter1 (Bn) -> cols 2,3
    READ_BQ(pB, 4, Bc_h0, Bc_l0, Bc_h1, Bc_l1);
    QMFMA(Bn_h0, Bn_l0, Bn_h1, Bn_l1, 2);

    // ---- A split+write for tile t+1 (x loads aged ~2 quarters; WAR on so
    // safe: so's last readers drained before mid-barrier(t-1), and any wave
    // here has passed that barrier) ----
    if (t < 63) { ASPLIT_WRITE(so); }

    // q2: read quarter3 -> Bn ; MFMA quarter2 (Bc) -> cols 4,5
    READ_BQ(pB, 6, Bn_h0, Bn_l0, Bn_h1, Bn_l1);
    QMFMA(Bc_h0, Bc_l0, Bc_h1, Bc_l1, 4);

    // ---- mid-iter sync: quarter reads + A ds_writes drained (lgkm0),
    // B GLDS landed (vmcnt0), then barrier (collective). ----
    asm volatile("s_waitcnt lgkmcnt(0)" ::: "memory");
    if (t < 63) { asm volatile("s_waitcnt vmcnt(0)" ::: "memory"); }
    asm volatile("s_barrier" ::: "memory");

    // read quarter0(t+1) from the just-landed buffer (Bc is dead) --
    // overlaps with q3's reg-only MFMAs below
    if (t < 63) {
      const char* pBn = smem + so + ABYTES + wn * 8192 + foff;
      READ_BQ(pBn, 0, Bc_h0, Bc_l0, Bc_h1, Bc_l1);
    }

    // q3: MFMA quarter3 (Bn) -> cols 6,7
    QMFMA(Bn_h0, Bn_l0, Bn_h1, Bn_l1, 6);

    // read A(t+1) from so (written this iter, drained at mid-barrier)
    if (t < 63) {
      const char* pAn = smem + so + wm * 4096 + foff;
#pragma unroll
      for (int mt = 0; mt < 4; ++mt) {
        A_h[mt] = *(const bf16x8_t*)(pAn + mt * 1024);
        A_l[mt] = *(const bf16x8_t*)(pAn + 16384 + mt * 1024);
      }
    }
  }

  // ---- epilogue: C/D layout col = lane&15, row = (lane>>4)*4 + reg ----
  const int orow0 = bm * 256 + wm * 64;
  const int ocol0 = bn * 256 + wn * 128;
#pragma unroll
  for (int nt = 0; nt < 8; ++nt) {
    const int col = ocol0 + nt * 16 + l15;
    const float b2 = bias2[col];
#pragma unroll
    for (int mt = 0; mt < 4; ++mt) {
      const int row = orow0 + mt * 16 + kl * 4;
#pragma unroll
      for (int r = 0; r < 4; ++r) {
        float z = acc[mt][nt][r] + b2;
        // tanh(z) = 1 - 2/(exp(2z)+1)
        float e = __expf(2.0f * z);
        out[(size_t)(row + r) * DIM + col] = 1.0f - 2.0f / (e + 1.0f);
      }
    }
  }
}

// ============================================================================
extern "C" void kernel_launch(void* const* d_in, const int* in_sizes, int n_in,
                              void* d_out, int out_size, void* d_ws, size_t ws_size,
                              hipStream_t stream) {
  const float* x   = (const float*)d_in[0];
  const float* hdw = (const float*)d_in[1];
  const float* W   = (const float*)d_in[2];
  const float* b   = (const float*)d_in[3];
  float* out = (float*)d_out;

  // workspace layout (~16.01 MB): W splits + bias2 only (x-split folded
  // into the GEMM's A staging)
  char* ws = (char*)d_ws;
  unsigned short* wThi = (unsigned short*)ws;                    // 8 MB
  unsigned short* wTlo = wThi + (size_t)DIM * DIM;               // 8 MB
  float*          bias2 = (float*)(wTlo + (size_t)DIM * DIM);    // 8 KB

  prep_fused_kernel<<<4104, 256, 0, stream>>>(hdw, W, b, bias2, wThi, wTlo);
  gemm_pipe_kernel<<<dim3(BATCH / 256, DIM / 256), 512, 0, stream>>>(
      x, wThi, wTlo, bias2, out);
}

// Round 17
// 328.440 us; speedup vs baseline: 1.0697x; 1.0697x over previous
//
#include <hip/hip_runtime.h>

#define BATCH 8192
#define DIM   2048   // IN_DIM == OUT_DIM
#define DEPTH 5

// ============================================================================
// r16 = r10 verbatim (best verified: 326.8us total; GEMM 156us, MfmaUtil
// 60.9%, bank-conflicts 0). r13's prep-fold REVERTED: folding the x-split
// into the GEMM made it 8x-redundant (every bn-block re-splits the same
// bm rows) -> GEMM +54us > prep -30us. One-shot work stays in prep.
//
// GEMM: 256x256 tile, BK=32, 512 thr = 8 waves (4wm x 2wn), wave tile
// 64x128 = 4x8 frags of 16x16x32 bf16 MFMA, bf16x3 triple -> 96 MFMA/wave/
// K-tile. Register quarter-pipeline: 4 quarters (2 nt each); per quarter
// issue next quarter's 4 ds_reads then 24 MFMAs on previous quarter's regs
// (static ping-pong Bc/Bn sets, rule 20). Mid-iter lgkm0+vmcnt0+barrier
// after q2; B-quarter0(t+1) read overlaps q3's reg-only MFMAs; A(t+1) read
// after q3. One barrier/iter.
//
// LDS: 2-deep x 64 KB buffers (A 32 KB @0, B 32 KB @32768). Swizzle: phys
// granule = logical ^ ((row>>1)&3), via inverse-swizzled GLOBAL source
// granule (rule 21) + swizzled ds_read offset. Measured 0 conflicts.
//
// Hazards (verified r10 on HW):
//  RAW tile t+1: staged at top of t, vmcnt(0)+barrier(mid-t) before reads.
//  WAR stage(t+2)->buf t&1: readers drained before mid-barrier(t).
//  vmcnt ledger: only stage(t+1)'s 8 loads outstanding at mid-iter drain,
//  aged ~3000 cyc >> 900-cyc HBM miss -> wait ~free.
// ============================================================================

#define BUFSZ  65536
#define ABYTES 32768

typedef short bf16x8_t __attribute__((ext_vector_type(8)));
typedef float f32x4_t  __attribute__((ext_vector_type(4)));

// ---- bf16 split helpers (RNE, bit-manip) ----
__device__ __forceinline__ unsigned short f2bf(float f) {
  unsigned u = __float_as_uint(f);
  u += 0x7fffu + ((u >> 16) & 1u);
  return (unsigned short)(u >> 16);
}
__device__ __forceinline__ float bf2f(unsigned short h) {
  return __uint_as_float(((unsigned)h) << 16);
}

// ============================================================================
// Fused prep (one dispatch) -- r10 version (verified r4/r7/r8/r10):
//  blocks [0, 8192)      : split x -> xhi/xlo, row-major [8192][2048] bf16
//  blocks [8192, 12288)  : W (KxN) -> transpose+split -> whi/wlo [N][K] bf16
//  blocks [12288, 12296) : bias2[j] = b[j] + (1/2048)*prod_d cos(hdw[d,j,0])^2
// ============================================================================
__global__ void prep_fused_kernel(const float* __restrict__ x,
                                  const float* __restrict__ hdw,
                                  const float* __restrict__ W,
                                  const float* __restrict__ bias,
                                  float* __restrict__ bias2,
                                  unsigned short* __restrict__ xhi,
                                  unsigned short* __restrict__ xlo,
                                  unsigned short* __restrict__ whi,
                                  unsigned short* __restrict__ wlo) {
  __shared__ float tile[32][33];
  const int b = blockIdx.x;
  const int tid = threadIdx.x;

  if (b < 8192) {  // ---- split x, row-major ----
    size_t g = (size_t)b * 256 + tid;       // 8-elem chunk id
    const float4* xp = (const float4*)(x + g * 8);
    float4 v0 = xp[0], v1 = xp[1];
    float v[8] = {v0.x, v0.y, v0.z, v0.w, v1.x, v1.y, v1.z, v1.w};
    bf16x8_t h, lo;
#pragma unroll
    for (int j = 0; j < 8; ++j) {
      unsigned short hj = f2bf(v[j]);
      h[j] = (short)hj;
      lo[j] = (short)f2bf(v[j] - bf2f(hj));
    }
    ((bf16x8_t*)xhi)[g] = h;
    ((bf16x8_t*)xlo)[g] = lo;
  } else if (b < 12288) {  // ---- transpose + split W -> [N][K] ----
    const int t = b - 8192;          // 4096 tiles of 32x32
    const int k0 = (t >> 6) * 32;
    const int n0 = (t & 63) * 32;
    const int tx = tid & 31;   // n within tile
    const int ty = tid >> 5;   // k within tile (8 rows/iter)
#pragma unroll
    for (int r = 0; r < 32; r += 8)
      tile[ty + r][tx] = W[(size_t)(k0 + ty + r) * DIM + n0 + tx];
    __syncthreads();
    const int n = tid >> 3;          // 0..31
    const int kq = (tid & 7) * 4;    // 0..28
    ushort4 hv, lv;
    float vv0 = tile[kq + 0][n], vv1 = tile[kq + 1][n];
    float vv2 = tile[kq + 2][n], vv3 = tile[kq + 3][n];
    hv.x = f2bf(vv0); lv.x = f2bf(vv0 - bf2f(hv.x));
    hv.y = f2bf(vv1); lv.y = f2bf(vv1 - bf2f(hv.y));
    hv.z = f2bf(vv2); lv.z = f2bf(vv2 - bf2f(hv.z));
    hv.w = f2bf(vv3); lv.w = f2bf(vv3 - bf2f(hv.w));
    const size_t o = (size_t)(n0 + n) * DIM + k0 + kq;
    *(ushort4*)(whi + o) = hv;
    *(ushort4*)(wlo + o) = lv;
  } else {  // ---- bias2 (scan preserves axis-1 uniformity -> rolls cancel) ----
    int j = (b - 12288) * 256 + tid;
    float p = 1.0f;
#pragma unroll
    for (int d = 0; d < DEPTH; ++d)
      p *= cosf(hdw[(size_t)d * DIM * DIM + (size_t)j * DIM]);
    bias2[j] = bias[j] + p * p * (1.0f / 2048.0f);
  }
}

// ---- async global->LDS, 16B per lane, LDS dest = wave-uniform base + lane*16
#define GLDS(SRC, OFF)                                                         \
  __builtin_amdgcn_global_load_lds(                                            \
      (const __attribute__((address_space(1))) unsigned int*)(SRC),            \
      (__attribute__((address_space(3))) unsigned int*)(smem + (OFF)), 16, 0, 0)

#define MFMA16(A, B, C) __builtin_amdgcn_mfma_f32_16x16x32_bf16((A), (B), (C), 0, 0, 0)

// stage one 64 KB tile (k-element offset KO) into buffer at byte SO
#define STAGE(KO, SO)                                                          \
  do {                                                                         \
    GLDS(sAh + (KO),             (SO) + 0              + wdst);                \
    GLDS(sAh + 128 * DIM + (KO), (SO) + 8192           + wdst);                \
    GLDS(sAl + (KO),             (SO) + 16384          + wdst);                \
    GLDS(sAl + 128 * DIM + (KO), (SO) + 24576          + wdst);                \
    GLDS(sBh + (KO),             (SO) + ABYTES + 0     + wdst);                \
    GLDS(sBh + 128 * DIM + (KO), (SO) + ABYTES + 8192  + wdst);                \
    GLDS(sBl + (KO),             (SO) + ABYTES + 16384 + wdst);                \
    GLDS(sBl + 128 * DIM + (KO), (SO) + ABYTES + 24576 + wdst);                \
  } while (0)

// read one B quarter (nt = NT, NT+1) from buffer base PB into 4 named regs
#define READ_BQ(PB, NT, H0, L0, H1, L1)                                        \
  do {                                                                         \
    H0 = *(const bf16x8_t*)((PB) + (NT) * 1024);                               \
    L0 = *(const bf16x8_t*)((PB) + 16384 + (NT) * 1024);                       \
    H1 = *(const bf16x8_t*)((PB) + ((NT) + 1) * 1024);                         \
    L1 = *(const bf16x8_t*)((PB) + 16384 + ((NT) + 1) * 1024);                 \
  } while (0)

// 24 MFMA: quarter with B regs (H0,L0,H1,L1) into acc columns C0, C0+1
#define QMFMA(H0, L0, H1, L1, C0)                                              \
  do {                                                                         \
    __builtin_amdgcn_s_setprio(1);                                             \
    _Pragma("unroll")                                                          \
    for (int mt = 0; mt < 4; ++mt) {                                           \
      acc[mt][C0]     = MFMA16(A_h[mt], H0, acc[mt][C0]);                      \
      acc[mt][C0]     = MFMA16(A_h[mt], L0, acc[mt][C0]);                      \
      acc[mt][C0]     = MFMA16(A_l[mt], H0, acc[mt][C0]);                      \
      acc[mt][C0 + 1] = MFMA16(A_h[mt], H1, acc[mt][C0 + 1]);                  \
      acc[mt][C0 + 1] = MFMA16(A_h[mt], L1, acc[mt][C0 + 1]);                  \
      acc[mt][C0 + 1] = MFMA16(A_l[mt], H1, acc[mt][C0 + 1]);                  \
    }                                                                          \
    __builtin_amdgcn_s_setprio(0);                                             \
  } while (0)

__global__ __launch_bounds__(512, 2) void gemm_pipe_kernel(
    const unsigned short* __restrict__ Ah, const unsigned short* __restrict__ Al,
    const unsigned short* __restrict__ Bh, const unsigned short* __restrict__ Bl,
    const float* __restrict__ bias2, float* __restrict__ out) {
  __shared__ float4 smem4[2 * BUFSZ / 16];
  char* smem = (char*)smem4;

  const int tid  = threadIdx.x;
  const int lane = tid & 63;
  const int wave = tid >> 6;
  const int wm   = wave >> 1;      // 0..3 : 64-row strip within 256
  const int wn   = wave & 1;       // 0..1 : 128-col strip within 256
  const int l15  = lane & 15;
  const int kl   = lane >> 4;
  const int bm = blockIdx.x;       // 32 strips of 256 rows
  const int bn = blockIdx.y;       // 8 strips of 256 cols

  // ---- per-lane staging sources (inverse-swizzled global granule) ----
  const int rsub = wave * 16 + (lane >> 2);                 // 0..127
  const int kg   = ((lane & 3) ^ ((lane >> 3) & 3)) * 8;    // element offset
  const unsigned short* sAh = Ah + ((size_t)(bm * 256 + rsub)) * DIM + kg;
  const unsigned short* sAl = Al + ((size_t)(bm * 256 + rsub)) * DIM + kg;
  const unsigned short* sBh = Bh + ((size_t)(bn * 256 + rsub)) * DIM + kg;
  const unsigned short* sBl = Bl + ((size_t)(bn * 256 + rsub)) * DIM + kg;
  const unsigned wdst = wave * 1024;   // wave-uniform byte base per instr

  // ---- per-lane fragment read offset (matching swizzle) ----
  const int foff = l15 * 64 + ((kl * 16) ^ (((l15 >> 1) & 3) << 4));

  const f32x4_t vzero = {0.f, 0.f, 0.f, 0.f};
  f32x4_t acc[4][8];
#pragma unroll
  for (int i = 0; i < 4; ++i)
#pragma unroll
    for (int j = 0; j < 8; ++j) acc[i][j] = vzero;

  // fragment registers: A (current tile), B ping-pong quarter sets
  bf16x8_t A_h[4], A_l[4];
  bf16x8_t Bc_h0, Bc_l0, Bc_h1, Bc_l1;   // "current" set
  bf16x8_t Bn_h0, Bn_l0, Bn_h1, Bn_l1;   // "next" set

  // ---- prologue: stage tile 0 -> buf0, drain, preload A(0) + quarter0 ----
  STAGE(0, 0);
  asm volatile("s_waitcnt vmcnt(0)" ::: "memory");
  asm volatile("s_barrier" ::: "memory");
  {
    const char* pA0 = smem + wm * 4096 + foff;
#pragma unroll
    for (int mt = 0; mt < 4; ++mt) {
      A_h[mt] = *(const bf16x8_t*)(pA0 + mt * 1024);
      A_l[mt] = *(const bf16x8_t*)(pA0 + 16384 + mt * 1024);
    }
    const char* pB0 = smem + ABYTES + wn * 8192 + foff;
    READ_BQ(pB0, 0, Bc_h0, Bc_l0, Bc_h1, Bc_l1);
  }

#pragma unroll 1
  for (int t = 0; t < 64; ++t) {
    const unsigned bo = (unsigned)(t & 1) * BUFSZ;   // compute buffer
    const unsigned so = bo ^ BUFSZ;                  // stage buffer
    const char* pB = smem + bo + ABYTES + wn * 8192 + foff;

    // ---- stage tile t+1 at iter top ----
    if (t < 63) {
      const int ko = (t + 1) * 32;
      STAGE(ko, so);
    }

    // q0: read quarter1 -> Bn ; MFMA quarter0 (Bc) -> cols 0,1
    READ_BQ(pB, 2, Bn_h0, Bn_l0, Bn_h1, Bn_l1);
    QMFMA(Bc_h0, Bc_l0, Bc_h1, Bc_l1, 0);

    // q1: read quarter2 -> Bc ; MFMA quarter1 (Bn) -> cols 2,3
    READ_BQ(pB, 4, Bc_h0, Bc_l0, Bc_h1, Bc_l1);
    QMFMA(Bn_h0, Bn_l0, Bn_h1, Bn_l1, 2);

    // q2: read quarter3 -> Bn ; MFMA quarter2 (Bc) -> cols 4,5
    READ_BQ(pB, 6, Bn_h0, Bn_l0, Bn_h1, Bn_l1);
    QMFMA(Bc_h0, Bc_l0, Bc_h1, Bc_l1, 4);

    // ---- mid-iter sync: all tile-t LDS reads issued above are drained
    // (lgkm0), tile t+1's staging landed (vmcnt0), then barrier. ----
    asm volatile("s_waitcnt lgkmcnt(0)" ::: "memory");
    if (t < 63) { asm volatile("s_waitcnt vmcnt(0)" ::: "memory"); }
    asm volatile("s_barrier" ::: "memory");

    // read quarter0(t+1) from the just-landed buffer (Bc is dead) --
    // overlaps with q3's reg-only MFMAs below
    if (t < 63) {
      const char* pBn = smem + so + ABYTES + wn * 8192 + foff;
      READ_BQ(pBn, 0, Bc_h0, Bc_l0, Bc_h1, Bc_l1);
    }

    // q3: MFMA quarter3 (Bn) -> cols 6,7
    QMFMA(Bn_h0, Bn_l0, Bn_h1, Bn_l1, 6);

    // read A(t+1) (A regs dead after q3) -- ~150 cyc exposed at seam
    if (t < 63) {
      const char* pAn = smem + so + wm * 4096 + foff;
#pragma unroll
      for (int mt = 0; mt < 4; ++mt) {
        A_h[mt] = *(const bf16x8_t*)(pAn + mt * 1024);
        A_l[mt] = *(const bf16x8_t*)(pAn + 16384 + mt * 1024);
      }
    }
  }

  // ---- epilogue: C/D layout col = lane&15, row = (lane>>4)*4 + reg ----
  const int orow0 = bm * 256 + wm * 64;
  const int ocol0 = bn * 256 + wn * 128;
#pragma unroll
  for (int nt = 0; nt < 8; ++nt) {
    const int col = ocol0 + nt * 16 + l15;
    const float b2 = bias2[col];
#pragma unroll
    for (int mt = 0; mt < 4; ++mt) {
      const int row = orow0 + mt * 16 + kl * 4;
#pragma unroll
      for (int r = 0; r < 4; ++r) {
        float z = acc[mt][nt][r] + b2;
        // tanh(z) = 1 - 2/(exp(2z)+1)
        float e = __expf(2.0f * z);
        out[(size_t)(row + r) * DIM + col] = 1.0f - 2.0f / (e + 1.0f);
      }
    }
  }
}

// ============================================================================
extern "C" void kernel_launch(void* const* d_in, const int* in_sizes, int n_in,
                              void* d_out, int out_size, void* d_ws, size_t ws_size,
                              hipStream_t stream) {
  const float* x   = (const float*)d_in[0];
  const float* hdw = (const float*)d_in[1];
  const float* W   = (const float*)d_in[2];
  const float* b   = (const float*)d_in[3];
  float* out = (float*)d_out;

  // workspace layout (~80.01 MB)
  char* ws = (char*)d_ws;
  unsigned short* xhi  = (unsigned short*)ws;                    // 32 MB
  unsigned short* xlo  = xhi + (size_t)BATCH * DIM;              // 32 MB
  unsigned short* wThi = xlo + (size_t)BATCH * DIM;              // 8 MB
  unsigned short* wTlo = wThi + (size_t)DIM * DIM;               // 8 MB
  float*          bias2 = (float*)(wTlo + (size_t)DIM * DIM);    // 8 KB

  prep_fused_kernel<<<12296, 256, 0, stream>>>(
      x, hdw, W, b, bias2, xhi, xlo, wThi, wTlo);
  gemm_pipe_kernel<<<dim3(BATCH / 256, DIM / 256), 512, 0, stream>>>(
      xhi, xlo, wThi, wTlo, bias2, out);
}